// Round 8
// baseline (332.574 us; speedup 1.0000x reference)
//
#include <hip/hip_runtime.h>
#include <hip/hip_bf16.h>

#define T_DIM 200
#define U_DIM 100
#define U1    101
#define H_DIM 320
#define K_INNER 512
#define V_DIM 1000
#define B_DIM 4
#define ND 300            // diagonals d = t+u in [0, 299]
#define ROWS 48           // 12 t x 4 u per block (R2-proven tile)
#define XPITCH 520        // 512 fp8 + 8B pad: conflict-free + imm-offset addressable
#define CHUNK 8           // dp: diagonals per LDS chunk

typedef unsigned short ushort_t;
typedef unsigned char uchar_t;
typedef unsigned int uint32;
typedef long lfrag;       // 8 x fp8 = 2 VGPRs

typedef float ffrag4 __attribute__((ext_vector_type(4)));
typedef int   ifrag  __attribute__((ext_vector_type(8)));   // 32 x fp8 = 8 VGPRs

#define LOG2E   1.4426950408889634f
#define LOG2E16 (1.4426950408889634f * 0.0625f)   // LOG2E/16 (W2 packed with x16 scale)
#define LN2     0.6931471805599453f

__device__ __forceinline__ float tanh_fast(float x) {
  float e = __expf(2.0f * x);                 // inf-safe: e=inf -> 1, e=0 -> -1
  return 1.0f - __fdividef(2.0f, e + 1.0f);
}

__device__ __forceinline__ uint2 pk_fp8x8(float t0, float t1, float t2, float t3,
                                          float t4, float t5, float t6, float t7) {
  uint2 r;
  r.x = (uint32)__builtin_amdgcn_cvt_pk_fp8_f32(t0, t1, 0, false);
  r.x = (uint32)__builtin_amdgcn_cvt_pk_fp8_f32(t2, t3, (int)r.x, true);
  r.y = (uint32)__builtin_amdgcn_cvt_pk_fp8_f32(t4, t5, 0, false);
  r.y = (uint32)__builtin_amdgcn_cvt_pk_fp8_f32(t6, t7, (int)r.y, true);
  return r;
}

// lane i <- lane i-1 (wave_shr:1 DPP, VALU-speed); invalid lane 0 gets `oldv`
__device__ __forceinline__ float dpp_up1(float v, float oldv) {
  return __int_as_float(__builtin_amdgcn_update_dpp(
      __float_as_int(oldv), __float_as_int(v), 0x138, 0xf, 0xf, false));
}

// ---------------- fused prep:
//   blocks [0,100):   h_enc projection (8 rows each) -- b1 FOLDED IN:
//                     hEnc := enc@W1[:H] + b1
//   blocks [100,151): h_dec projection (8 rows each)
//   blocks [151,215): W2 transpose-pack (x16 scale) for DIRECT-TO-REG loads in
//     the MX-scaled joint K-loop. Region index R(ct,ks4,w,cb) = ct*64+ks4*16+
//     w*4+cb -> 2KB, two coalesced 1KB halves (part = k-within-block / 16):
//       off = R*2048 + part*1024 + lane*16 + (k&15),  lane = quad*16+l15
//     so lane (quad,l15) assembles its v8i32 B fragment (col = cb*16+l15,
//     k = ks4*128 + quad*32 + 0..31) from two dwordx4 loads at +0 / +1024.
__global__ __launch_bounds__(512)
void prep_kernel(const float* __restrict__ enc, const float* __restrict__ dec,
                 const float* __restrict__ W1, const float* __restrict__ W2,
                 const float* __restrict__ b1,
                 float* __restrict__ hEnc, float* __restrict__ hDec,
                 uchar_t* __restrict__ W2f8)
{
  __shared__ union { float sIn[8][H_DIM]; float sW[8][1024]; } sh;
  const int tid = threadIdx.x;
  const int blk = blockIdx.x;

  if (blk < 151) {
    const float* inp; float* outp; int nRows, rowOff, b0;
    if (blk < 100) { inp = enc; outp = hEnc; nRows = B_DIM * T_DIM; rowOff = 0;     b0 = blk; }
    else           { inp = dec; outp = hDec; nRows = B_DIM * U1;    rowOff = H_DIM; b0 = blk - 100; }
    const int r0 = b0 * 8;
    for (int i = tid; i < 8 * H_DIM; i += 512) {
      int r = i / H_DIM, k = i - r * H_DIM;
      int rr = r0 + r;
      sh.sIn[r][k] = (rr < nRows) ? inp[(size_t)rr * H_DIM + k] : 0.0f;
    }
    __syncthreads();
    const int c = tid;  // 0..511
    float acc[8];
#pragma unroll
    for (int r = 0; r < 8; ++r) acc[r] = 0.0f;
    const float* Wp = W1 + (size_t)rowOff * K_INNER + c;
    for (int k = 0; k < H_DIM; k += 4) {
      float w0 = Wp[(size_t)(k + 0) * K_INNER];
      float w1 = Wp[(size_t)(k + 1) * K_INNER];
      float w2 = Wp[(size_t)(k + 2) * K_INNER];
      float w3 = Wp[(size_t)(k + 3) * K_INNER];
#pragma unroll
      for (int r = 0; r < 8; ++r) {
        float4 s = *(const float4*)&sh.sIn[r][k];
        acc[r] = fmaf(s.w, w3, fmaf(s.z, w2, fmaf(s.y, w1, fmaf(s.x, w0, acc[r]))));
      }
    }
    const float bb = (rowOff == 0) ? b1[c] : 0.0f;   // fold b1 into hEnc only
#pragma unroll
    for (int r = 0; r < 8; ++r) {
      int rr = r0 + r;
      if (rr < nRows) outp[(size_t)rr * K_INNER + c] = acc[r] + bb;
    }
  } else {
    // W2 pack: kchunk kc covers k in [kc*8, kc*8+8); LDS transpose; x16 scale
    // (raw |w| <= 0.045 sits in e4m3's denormal zone; x16 -> +-0.71, normal)
    const int kc = blk - 151;
    for (int i = tid; i < 8 * 1024; i += 512) {
      int r = i >> 10, n = i & 1023;
      sh.sW[r][n] = (n < V_DIM) ? W2[(size_t)(kc * 8 + r) * V_DIM + n] : 0.0f;
    }
    __syncthreads();
    // k = kc*8 + r:  ks4 = k>>7, quad = (k>>5)&3, i = k&31, part = i>>4, io = i&15
    const int ks4 = kc >> 4, qd = (kc >> 2) & 3, part = (kc >> 1) & 1, io = (kc & 1) * 8;
#pragma unroll
    for (int h = 0; h < 2; ++h) {
      int n = tid + h * 512;
      uint2 pk = pk_fp8x8(sh.sW[0][n] * 16.f, sh.sW[1][n] * 16.f,
                          sh.sW[2][n] * 16.f, sh.sW[3][n] * 16.f,
                          sh.sW[4][n] * 16.f, sh.sW[5][n] * 16.f,
                          sh.sW[6][n] * 16.f, sh.sW[7][n] * 16.f);
      const int ct = n >> 8, w = (n >> 6) & 3, cb = (n >> 4) & 3, l15 = n & 15;
      const int R = ct * 64 + ks4 * 16 + w * 4 + cb;
      const size_t off = (size_t)R * 2048 + part * 1024 + (qd * 16 + l15) * 16 + io;
      *(uint2*)&W2f8[off] = pk;
    }
  }
}

// ---------------- fused joint, MX-scaled fp8 (16x16x128, unity e8m0 scales),
// 48-row tile, (256,2) -- R7 hardened skeleton + register-demand cut (r16).
// R7 closed the occupancy arithmetic: 124 arch-VGPR + 48 AGPR (acc) = 172/wave
// -> 512/172 = 2.97 -> 2 waves/SIMD. TWO registers over the 3-wave boundary.
// This round cuts ~24 regs with the R5/R6-proven (correctness-wise) tricks,
// applied as a minimal diff to the stable skeleton:
//   - blankV (12 regs) -> wave0/l15==0 stores acc[rb][0] to sred[0][row][1]
//     at end of ct0 (sred now a SEPARATE 3KB array, not unioned with sX)
//   - labelA (12 regs) -> the unique matching lane stores the label logit to
//     sred[0][row][2] (slot pre-zeroed); kills 192 cndmask+add + its reduce
// K-loop/staging/addressing byte-identical to R7 (no restructure -> no
// scratch-demotion risk). min-waves stays 2: no forced cap, no cliff.
__global__ __launch_bounds__(256, 2)
void joint_kernel(const float* __restrict__ hEnc, const float* __restrict__ hDec,
                  const uchar_t* __restrict__ W2f8,
                  const float* __restrict__ b2, const int* __restrict__ tokens,
                  float* __restrict__ pD)
{
  __shared__ __align__(16) uchar_t sX[ROWS * XPITCH];   // 48 x 520 = 24,960 B
  __shared__ float sred[4][ROWS][4];                    // 3 KB; [1]=blank [2]=label

  const int tid = threadIdx.x;
  const int b  = blockIdx.z;
  const int t0 = blockIdx.y * 12;   // 17 blocks cover 200 (writes guarded)
  const int u0 = blockIdx.x * 4;    // 26 blocks cover 104 >= 101
  const int wave = tid >> 6;
  const int lane = tid & 63;
  const int l15 = lane & 15;
  const int quad = lane >> 4;

  // per-wave global B base: region R = g*16 + wave*4 + cb, lane-major 16B.
  // All offsets are compile-time constants folded per unrolled step (R7-exact).
  const uchar_t* gB = W2f8 + (size_t)wave * 8192 + (size_t)lane * 16;
  ifrag bv0[4], bv1[4];             // NAMED B double-buffers (64 VGPR)

#define LOADB(buf_, g_)                                                        \
  {                                                                            \
    *(int4*)&buf_[0]         = *(const int4*)(gB + (size_t)((g_)*16 + 0) * 2048);          \
    *(((int4*)&buf_[0]) + 1) = *(const int4*)(gB + (size_t)((g_)*16 + 0) * 2048 + 1024);   \
    *(int4*)&buf_[1]         = *(const int4*)(gB + (size_t)((g_)*16 + 1) * 2048);          \
    *(((int4*)&buf_[1]) + 1) = *(const int4*)(gB + (size_t)((g_)*16 + 1) * 2048 + 1024);   \
    *(int4*)&buf_[2]         = *(const int4*)(gB + (size_t)((g_)*16 + 2) * 2048);          \
    *(((int4*)&buf_[2]) + 1) = *(const int4*)(gB + (size_t)((g_)*16 + 2) * 2048 + 1024);   \
    *(int4*)&buf_[3]         = *(const int4*)(gB + (size_t)((g_)*16 + 3) * 2048);          \
    *(((int4*)&buf_[3]) + 1) = *(const int4*)(gB + (size_t)((g_)*16 + 3) * 2048 + 1024);   \
  }

  // preload b2 (scaled) + tokens to regs (retire at the staging barrier ->
  // in-loop vmcnt accounting sees only LOADB issues)
  float b2s[4][4];
#pragma unroll
  for (int ct = 0; ct < 4; ++ct)
#pragma unroll
    for (int cb = 0; cb < 4; ++cb) {
      int v = ct * 256 + wave * 64 + cb * 16 + l15;
      b2s[ct][cb] = (v < V_DIM) ? b2[v] * LOG2E : -1e30f;
    }
  int tokv[4];
#pragma unroll
  for (int j = 0; j < 4; ++j)
    tokv[j] = (u0 + j < U_DIM) ? tokens[b * U_DIM + u0 + j] : -1;

  // ---- X staging: per pass a wave owns one row; G = lane -> conflict-free
  // (hEnc already contains +b1)
  for (int i = tid; i < ROWS * 64; i += 256) {
    const int row = i >> 6;           // 0..47
    const int G = i & 63;
    const int tcl = min(t0 + (row >> 2), T_DIM - 1);
    const int ucl = min(u0 + (row & 3), U1 - 1);
    const float* er = hEnc + (size_t)(b * T_DIM + tcl) * K_INNER;
    const float* dr = hDec + (size_t)(b * U1 + ucl) * K_INNER;
    const int k = G << 3;
    float4 e0 = *(const float4*)(er + k);
    float4 e1 = *(const float4*)(er + k + 4);
    float4 d0 = *(const float4*)(dr + k);
    float4 d1 = *(const float4*)(dr + k + 4);
    uint2 pk = pk_fp8x8(tanh_fast(e0.x + d0.x), tanh_fast(e0.y + d0.y),
                        tanh_fast(e0.z + d0.z), tanh_fast(e0.w + d0.w),
                        tanh_fast(e1.x + d1.x), tanh_fast(e1.y + d1.y),
                        tanh_fast(e1.z + d1.z), tanh_fast(e1.w + d1.w));
    *(uint2*)&sX[row * XPITCH + (G << 3)] = pk;
  }
  if (tid < ROWS) sred[0][tid][2] = 0.0f;   // label slot init (u>=U rows keep 0)

  // issue step-0 B loads: overlap the barrier (worst case drained there; then
  // the in-loop vmcnt(8) accounting is still correct -- it counts newest-8)
  LOADB(bv0, 0)
  __syncthreads();

  // A base: lane (l15,quad) holds row l15, k = ks4*128 + quad*32 + 0..31
  const uchar_t* aB = &sX[l15 * XPITCH + quad * 32];

  float sumexp[3][4];
#pragma unroll
  for (int i = 0; i < 3; ++i)
#pragma unroll
    for (int j = 0; j < 4; ++j) sumexp[i][j] = 0.0f;

  union AF { ifrag f; lfrag q[4]; };
  AF av0, av1, av2;                 // NAMED A fragments (24 VGPR)
  ffrag4 acc[3][4];

#define LDA(dst_, rb_, ks4_)                                                 \
  {                                                                          \
    const uchar_t* ap_ = aB + (rb_) * (16 * XPITCH) + (ks4_) * 128;          \
    dst_.q[0] = *(const lfrag*)(ap_);                                        \
    dst_.q[1] = *(const lfrag*)(ap_ + 8);                                    \
    dst_.q[2] = *(const lfrag*)(ap_ + 16);                                   \
    dst_.q[3] = *(const lfrag*)(ap_ + 24);                                   \
  }

#define MM1(rb_, cb_, AV, CUR)                                               \
  acc[rb_][cb_] = __builtin_amdgcn_mfma_scale_f32_16x16x128_f8f6f4(          \
      AV.f, CUR[cb_], acc[rb_][cb_], 0, 0, 0, 0x7f7f7f7f, 0, 0x7f7f7f7f);

  // one K-step: g = ct*4+ks4 (literal after the explicit 4-step sequence);
  // prefetch next step into NXT, consume CUR. vmcnt(8) = current 8 resident.
#define STEPK(g_, ks4_, CUR, NXT)                                            \
  {                                                                          \
    if ((g_) < 15) LOADB(NXT, (g_) + 1)                                      \
    LDA(av0, 0, ks4_)                                                        \
    LDA(av1, 1, ks4_)                                                        \
    LDA(av2, 2, ks4_)                                                        \
    if ((g_) < 15) { asm volatile("s_waitcnt vmcnt(8)" ::: "memory"); }      \
    else           { asm volatile("s_waitcnt vmcnt(0)" ::: "memory"); }      \
    __builtin_amdgcn_s_setprio(1);                                           \
    MM1(0, 0, av0, CUR) MM1(0, 1, av0, CUR) MM1(0, 2, av0, CUR) MM1(0, 3, av0, CUR) \
    MM1(1, 0, av1, CUR) MM1(1, 1, av1, CUR) MM1(1, 2, av1, CUR) MM1(1, 3, av1, CUR) \
    MM1(2, 0, av2, CUR) MM1(2, 1, av2, CUR) MM1(2, 2, av2, CUR) MM1(2, 3, av2, CUR) \
    __builtin_amdgcn_s_setprio(0);                                           \
  }

#pragma unroll
  for (int ct = 0; ct < 4; ++ct) {
    ffrag4 zero4 = {0.0f, 0.0f, 0.0f, 0.0f};
#pragma unroll
    for (int rb = 0; rb < 3; ++rb)
#pragma unroll
      for (int cb = 0; cb < 4; ++cb) acc[rb][cb] = zero4;

    STEPK(ct * 4 + 0, 0, bv0, bv1)
    STEPK(ct * 4 + 1, 1, bv1, bv0)
    STEPK(ct * 4 + 2, 2, bv0, bv1)
    STEPK(ct * 4 + 3, 3, bv1, bv0)

    // epilogue: acc = 16 x true logit (W2 scale); next ct's first B loads are
    // already in flight -> free latency cover. Label logit: the unique
    // matching lane ds_writes it (no accumulate, no reduce). Blank column:
    // wave0/l15==0 stores acc[rb][0] directly at end of ct0.
#pragma unroll
    for (int cb = 0; cb < 4; ++cb) {
      const int v = ct * 256 + wave * 64 + cb * 16 + l15;
      const float bs = b2s[ct][cb];
#pragma unroll
      for (int rb = 0; rb < 3; ++rb)
#pragma unroll
        for (int reg = 0; reg < 4; ++reg) {
          float a = acc[rb][cb][reg];
          sumexp[rb][reg] += exp2f(fmaf(a, LOG2E16, bs));
          if (v == tokv[reg]) sred[0][rb * 16 + quad * 4 + reg][2] = a;
        }
    }
    if (ct == 0 && wave == 0 && l15 == 0) {
#pragma unroll
      for (int rb = 0; rb < 3; ++rb)
#pragma unroll
        for (int reg = 0; reg < 4; ++reg)
          sred[0][rb * 16 + quad * 4 + reg][1] = acc[rb][0][reg];
    }
  }
#undef STEPK
#undef MM1
#undef LDA
#undef LOADB

#pragma unroll
  for (int mask = 1; mask <= 8; mask <<= 1) {
#pragma unroll
    for (int rb = 0; rb < 3; ++rb)
#pragma unroll
      for (int reg = 0; reg < 4; ++reg)
        sumexp[rb][reg] += __shfl_xor(sumexp[rb][reg], mask, 64);
  }

  if (l15 == 0) {
#pragma unroll
    for (int rb = 0; rb < 3; ++rb)
#pragma unroll
      for (int reg = 0; reg < 4; ++reg)
        sred[wave][rb * 16 + quad * 4 + reg][0] = sumexp[rb][reg];
  }
  __syncthreads();
  if (tid < ROWS) {
    float S  = sred[0][tid][0] + sred[1][tid][0] + sred[2][tid][0] + sred[3][tid][0];
    float Bl = sred[0][tid][1];
    float Lb = sred[0][tid][2];
    int t = t0 + (tid >> 2);
    int u = u0 + (tid & 3);
    if (t < T_DIM && u < U1) {
      float lse2 = __log2f(S);                 // S = sum(exp(true logit))
      int tok = (u < U_DIM) ? tokens[b * U_DIM + u] : 0;
      int d = t + u;
      size_t idx = (((size_t)b * ND + d) * 128 + u) * 2;
      pD[idx]     = fmaf(Bl, LOG2E16, b2[0]   * LOG2E) - lse2;   // blank
      pD[idx + 1] = fmaf(Lb, LOG2E16, b2[tok] * LOG2E) - lse2;   // label
    }
  }
}

// ---------------- RNNT DP, log2 domain, LDS-staged triple-buffered chunks.
// r9 residual (~100us, ~330cyc/step): per-step ds_read latency sat on the serial
// chain. Fix: batch all 8 q-reads of a chunk into registers (unrolled float4
// qv[8]) before the 8-step chain -- LDS latency paid once per chunk.
__global__ __launch_bounds__(256)
void dp_kernel(const float* __restrict__ pD,
               const int* __restrict__ outLen, const int* __restrict__ tokLen,
               float* __restrict__ outLoss)
{
  __shared__ __align__(16) float sD[4][3][CHUNK * 256];   // 96 KB triple buffer
  __shared__ float llsh[B_DIM];
  const int tid = threadIdx.x;
  const int wv = tid >> 6;                  // wave = batch
  const int lane = tid & 63;
  const float* src = pD + (size_t)wv * ND * 256;
  const int tIdx = outLen[wv] - 1;
  const int uIdx = tokLen[wv];
  const int dStar = tIdx + uIdx;
  const float NEG = -1e30f;
  const float blkStar = src[((size_t)dStar * 128 + uIdx) * 2];

  float aE = (lane == 0) ? 0.0f : NEG;      // log2 domain
  float aO = NEG;
  float ll2 = 0.0f;
  if (dStar == 0 && lane == 0) ll2 = blkStar;

  const int uE = 2 * lane;

#define ISSUE(c, buf)                                                         \
  {                                                                           \
    const float* g_ = src + (size_t)(c) * (CHUNK * 256);                      \
    float* l_ = &sD[wv][(buf)][0];                                            \
    _Pragma("unroll")                                                         \
    for (int j_ = 0; j_ < CHUNK; ++j_)                                        \
      __builtin_amdgcn_global_load_lds(                                       \
        (const __attribute__((address_space(1))) void*)(g_ + j_ * 256 + lane * 4), \
        (__attribute__((address_space(3))) void*)(l_ + j_ * 256), 16, 0, 0);  \
  }

  ISSUE(0, 0)
  ISSUE(1, 1)
#pragma unroll 1
  for (int c = 0; c < 38; ++c) {
    { const int nc = c + 2; const int cc = nc <= 37 ? nc : 37; ISSUE(cc, nc % 3) }
    asm volatile("s_waitcnt vmcnt(16)" ::: "memory");   // chunk c resident
    const float* buf = &sD[wv][c % 3][0];
    float4 qv[CHUNK];
#pragma unroll
    for (int j = 0; j < CHUNK; ++j)
      qv[j] = *(const float4*)&buf[j * 256 + uE * 2];
#pragma unroll
    for (int j = 0; j < CHUNK; ++j) {
      const int d = c * CHUNK + 1 + j;
      float4 q = qv[j];
      // q = (B[uE], L[uE], B[uE+1], L[uE+1]) at source diag d-1
      float aO_up = dpp_up1(aO, NEG);
      float labUp = dpp_up1(q.w, NEG);                // L[uE-1] @ d-1
      // uE cell
      float bt0 = aE + q.x, lt0 = aO_up + labUp;
      float mx0 = fmaxf(bt0, lt0), mn0 = fminf(bt0, lt0);
      float r0 = mx0 + __log2f(1.0f + exp2f(mn0 - mx0));
      int te = d - uE;
      float nE = ((uE <= U_DIM) && (te >= 0) && (te < T_DIM)) ? r0 : NEG;
      // uO cell
      float bt1 = aO + q.z, lt1 = aE + q.y;
      float mx1 = fmaxf(bt1, lt1), mn1 = fminf(bt1, lt1);
      float r1 = mx1 + __log2f(1.0f + exp2f(mn1 - mx1));
      int to = te - 1;
      float nO = ((uE + 1 <= U_DIM) && (to >= 0) && (to < T_DIM)) ? r1 : NEG;
      aE = nE; aO = nO;
      if (d == dStar) {
        if (uIdx == uE)          ll2 = nE + blkStar;
        else if (uIdx == uE + 1) ll2 = nO + blkStar;
      }
    }
  }
#undef ISSUE

#pragma unroll
  for (int mask = 1; mask < 64; mask <<= 1) ll2 += __shfl_xor(ll2, mask, 64);
  if (lane == 0) llsh[wv] = ll2;
  __syncthreads();
  if (tid == 0)
    outLoss[0] = -(llsh[0] + llsh[1] + llsh[2] + llsh[3]) * 0.25f * LN2;
}

// ---------------- launch
extern "C" void kernel_launch(void* const* d_in, const int* in_sizes, int n_in,
                              void* d_out, int out_size, void* d_ws, size_t ws_size,
                              hipStream_t stream)
{
  const float* enc    = (const float*)d_in[0];
  const float* dec    = (const float*)d_in[1];
  const int*   tokens = (const int*)d_in[2];
  const int*   outLen = (const int*)d_in[3];
  const int*   tokLen = (const int*)d_in[4];
  const float* W1     = (const float*)d_in[5];
  const float* b1     = (const float*)d_in[6];
  const float* W2     = (const float*)d_in[7];
  const float* b2     = (const float*)d_in[8];
  float* out = (float*)d_out;

  char* ws = (char*)d_ws;
  float*   hEnc = (float*)(ws + 0);           // 800*512*4     = 1,638,400
  float*   hDec = (float*)(ws + 1638400);     // 404*512*4     =   827,392
  uchar_t* W2f8 = (uchar_t*)(ws + 2465792);   // 256 regions*2048 = 524,288 (16-aligned)
  float*   pD   = (float*)(ws + 2990080);     // 4*300*128*2*4 = 1,228,800
                                              // + 16KB tail pad for dp chunk-37 overread

  prep_kernel<<<dim3(215), dim3(512), 0, stream>>>(enc, dec, W1, W2, b1, hEnc, hDec, W2f8);
  joint_kernel<<<dim3(26, 17, B_DIM), dim3(256), 0, stream>>>(hEnc, hDec, W2f8, b2, tokens, pD);
  dp_kernel<<<dim3(1), dim3(256), 0, stream>>>(pD, outLen, tokLen, out);
}

// Round 9
// 243.204 us; speedup vs baseline: 1.3675x; 1.3675x over previous
//
#include <hip/hip_runtime.h>
#include <hip/hip_bf16.h>

#define T_DIM 200
#define U_DIM 100
#define U1    101
#define H_DIM 320
#define K_INNER 512
#define V_DIM 1000
#define B_DIM 4
#define ND 300            // diagonals d = t+u in [0, 299]
#define ROWS 48           // 12 t x 4 u per block (R2-proven tile)
#define XPITCH 520        // 512 fp8 + 8B pad: conflict-free + imm-offset addressable
#define CHUNK 8           // dp: diagonals per LDS chunk

typedef unsigned short ushort_t;
typedef unsigned char uchar_t;
typedef unsigned int uint32;
typedef long lfrag;       // 8 x fp8 = 2 VGPRs

typedef float ffrag4 __attribute__((ext_vector_type(4)));
typedef int   ifrag  __attribute__((ext_vector_type(8)));   // 32 x fp8 = 8 VGPRs

#define LOG2E   1.4426950408889634f
#define LOG2E16 (1.4426950408889634f * 0.0625f)   // LOG2E/16 (W2 packed with x16 scale)
#define LN2     0.6931471805599453f

__device__ __forceinline__ float tanh_fast(float x) {
  float e = __expf(2.0f * x);                 // inf-safe: e=inf -> 1, e=0 -> -1
  return 1.0f - __fdividef(2.0f, e + 1.0f);
}

__device__ __forceinline__ uint2 pk_fp8x8(float t0, float t1, float t2, float t3,
                                          float t4, float t5, float t6, float t7) {
  uint2 r;
  r.x = (uint32)__builtin_amdgcn_cvt_pk_fp8_f32(t0, t1, 0, false);
  r.x = (uint32)__builtin_amdgcn_cvt_pk_fp8_f32(t2, t3, (int)r.x, true);
  r.y = (uint32)__builtin_amdgcn_cvt_pk_fp8_f32(t4, t5, 0, false);
  r.y = (uint32)__builtin_amdgcn_cvt_pk_fp8_f32(t6, t7, (int)r.y, true);
  return r;
}

// lane i <- lane i-1 (wave_shr:1 DPP, VALU-speed); invalid lane 0 gets `oldv`
__device__ __forceinline__ float dpp_up1(float v, float oldv) {
  return __int_as_float(__builtin_amdgcn_update_dpp(
      __float_as_int(oldv), __float_as_int(v), 0x138, 0xf, 0xf, false));
}

// ---------------- fused prep:
//   blocks [0,100):   h_enc projection (8 rows each) -- b1 FOLDED IN:
//                     hEnc := enc@W1[:H] + b1
//   blocks [100,151): h_dec projection (8 rows each)
//   blocks [151,215): W2 transpose-pack (x16 scale) for DIRECT-TO-REG loads in
//     the MX-scaled joint K-loop. Region index R(ct,ks4,w,cb) = ct*64+ks4*16+
//     w*4+cb -> 2KB, two coalesced 1KB halves (part = k-within-block / 16):
//       off = R*2048 + part*1024 + lane*16 + (k&15),  lane = quad*16+l15
//     so lane (quad,l15) assembles its v8i32 B fragment (col = cb*16+l15,
//     k = ks4*128 + quad*32 + 0..31) from two dwordx4 loads at +0 / +1024.
__global__ __launch_bounds__(512)
void prep_kernel(const float* __restrict__ enc, const float* __restrict__ dec,
                 const float* __restrict__ W1, const float* __restrict__ W2,
                 const float* __restrict__ b1,
                 float* __restrict__ hEnc, float* __restrict__ hDec,
                 uchar_t* __restrict__ W2f8)
{
  __shared__ union { float sIn[8][H_DIM]; float sW[8][1024]; } sh;
  const int tid = threadIdx.x;
  const int blk = blockIdx.x;

  if (blk < 151) {
    const float* inp; float* outp; int nRows, rowOff, b0;
    if (blk < 100) { inp = enc; outp = hEnc; nRows = B_DIM * T_DIM; rowOff = 0;     b0 = blk; }
    else           { inp = dec; outp = hDec; nRows = B_DIM * U1;    rowOff = H_DIM; b0 = blk - 100; }
    const int r0 = b0 * 8;
    for (int i = tid; i < 8 * H_DIM; i += 512) {
      int r = i / H_DIM, k = i - r * H_DIM;
      int rr = r0 + r;
      sh.sIn[r][k] = (rr < nRows) ? inp[(size_t)rr * H_DIM + k] : 0.0f;
    }
    __syncthreads();
    const int c = tid;  // 0..511
    float acc[8];
#pragma unroll
    for (int r = 0; r < 8; ++r) acc[r] = 0.0f;
    const float* Wp = W1 + (size_t)rowOff * K_INNER + c;
    for (int k = 0; k < H_DIM; k += 4) {
      float w0 = Wp[(size_t)(k + 0) * K_INNER];
      float w1 = Wp[(size_t)(k + 1) * K_INNER];
      float w2 = Wp[(size_t)(k + 2) * K_INNER];
      float w3 = Wp[(size_t)(k + 3) * K_INNER];
#pragma unroll
      for (int r = 0; r < 8; ++r) {
        float4 s = *(const float4*)&sh.sIn[r][k];
        acc[r] = fmaf(s.w, w3, fmaf(s.z, w2, fmaf(s.y, w1, fmaf(s.x, w0, acc[r]))));
      }
    }
    const float bb = (rowOff == 0) ? b1[c] : 0.0f;   // fold b1 into hEnc only
#pragma unroll
    for (int r = 0; r < 8; ++r) {
      int rr = r0 + r;
      if (rr < nRows) outp[(size_t)rr * K_INNER + c] = acc[r] + bb;
    }
  } else {
    // W2 pack: kchunk kc covers k in [kc*8, kc*8+8); LDS transpose; x16 scale
    // (raw |w| <= 0.045 sits in e4m3's denormal zone; x16 -> +-0.71, normal)
    const int kc = blk - 151;
    for (int i = tid; i < 8 * 1024; i += 512) {
      int r = i >> 10, n = i & 1023;
      sh.sW[r][n] = (n < V_DIM) ? W2[(size_t)(kc * 8 + r) * V_DIM + n] : 0.0f;
    }
    __syncthreads();
    // k = kc*8 + r:  ks4 = k>>7, quad = (k>>5)&3, i = k&31, part = i>>4, io = i&15
    const int ks4 = kc >> 4, qd = (kc >> 2) & 3, part = (kc >> 1) & 1, io = (kc & 1) * 8;
#pragma unroll
    for (int h = 0; h < 2; ++h) {
      int n = tid + h * 512;
      uint2 pk = pk_fp8x8(sh.sW[0][n] * 16.f, sh.sW[1][n] * 16.f,
                          sh.sW[2][n] * 16.f, sh.sW[3][n] * 16.f,
                          sh.sW[4][n] * 16.f, sh.sW[5][n] * 16.f,
                          sh.sW[6][n] * 16.f, sh.sW[7][n] * 16.f);
      const int ct = n >> 8, w = (n >> 6) & 3, cb = (n >> 4) & 3, l15 = n & 15;
      const int R = ct * 64 + ks4 * 16 + w * 4 + cb;
      const size_t off = (size_t)R * 2048 + part * 1024 + (qd * 16 + l15) * 16 + io;
      *(uint2*)&W2f8[off] = pk;
    }
  }
}

// ---------------- fused joint, MX-scaled fp8 (16x16x128, unity e8m0 scales),
// 48-row tile, (256,2) -- R7 hardened skeleton + b2s->LDS (r17).
// R7 arithmetic: 124 arch-VGPR + 48 AGPR = 172/wave -> 2 waves/SIMD; the
// 3-wave boundary is <=170 total (ladder: R3 128->~3w, R5 148->3w, R7 172->2w).
// R8's epilogue-ds_write edit spilled (again) -> rule: NO new LDS writes or
// conditionals in the hot loop. This round's cut is the least invasive
// possible: b2s[4][4] (16 VGPR) becomes an LDS table sb2[1024] written during
// staging (same pattern as the proven sX staging, retires at the same
// barrier); the epilogue reads bs via ds_read at the already-computed index.
// labelA/blankV stay in registers EXACTLY as R7. 172-16 = 156 <= 170.
__global__ __launch_bounds__(256, 2)
void joint_kernel(const float* __restrict__ hEnc, const float* __restrict__ hDec,
                  const uchar_t* __restrict__ W2f8,
                  const float* __restrict__ b2, const int* __restrict__ tokens,
                  float* __restrict__ pD)
{
  __shared__ union SU {
    uchar_t X[ROWS * XPITCH];     // 48 x 520 = 24,960 B
    float red[4][ROWS][4];
  } sh;
  __shared__ float sb2[1024];     // b2 * LOG2E (padded with -1e30)

  const int tid = threadIdx.x;
  const int b  = blockIdx.z;
  const int t0 = blockIdx.y * 12;   // 17 blocks cover 200 (writes guarded)
  const int u0 = blockIdx.x * 4;    // 26 blocks cover 104 >= 101
  const int wave = tid >> 6;
  const int lane = tid & 63;
  const int l15 = lane & 15;
  const int quad = lane >> 4;

  // per-wave global B base: region R = g*16 + wave*4 + cb, lane-major 16B.
  // All offsets are compile-time constants folded per unrolled step (R7-exact).
  const uchar_t* gB = W2f8 + (size_t)wave * 8192 + (size_t)lane * 16;
  ifrag bv0[4], bv1[4];             // NAMED B double-buffers (64 VGPR)

#define LOADB(buf_, g_)                                                        \
  {                                                                            \
    *(int4*)&buf_[0]         = *(const int4*)(gB + (size_t)((g_)*16 + 0) * 2048);          \
    *(((int4*)&buf_[0]) + 1) = *(const int4*)(gB + (size_t)((g_)*16 + 0) * 2048 + 1024);   \
    *(int4*)&buf_[1]         = *(const int4*)(gB + (size_t)((g_)*16 + 1) * 2048);          \
    *(((int4*)&buf_[1]) + 1) = *(const int4*)(gB + (size_t)((g_)*16 + 1) * 2048 + 1024);   \
    *(int4*)&buf_[2]         = *(const int4*)(gB + (size_t)((g_)*16 + 2) * 2048);          \
    *(((int4*)&buf_[2]) + 1) = *(const int4*)(gB + (size_t)((g_)*16 + 2) * 2048 + 1024);   \
    *(int4*)&buf_[3]         = *(const int4*)(gB + (size_t)((g_)*16 + 3) * 2048);          \
    *(((int4*)&buf_[3]) + 1) = *(const int4*)(gB + (size_t)((g_)*16 + 3) * 2048 + 1024);   \
  }

  // tokens to regs (retire at the staging barrier)
  int tokv[4];
#pragma unroll
  for (int j = 0; j < 4; ++j)
    tokv[j] = (u0 + j < U_DIM) ? tokens[b * U_DIM + u0 + j] : -1;

  // b2 (scaled) -> LDS table (frees 16 VGPR vs the b2s register array)
  for (int i = tid; i < 1024; i += 256)
    sb2[i] = (i < V_DIM) ? b2[i] * LOG2E : -1e30f;

  // ---- X staging: per pass a wave owns one row; G = lane -> conflict-free
  // (hEnc already contains +b1)
  for (int i = tid; i < ROWS * 64; i += 256) {
    const int row = i >> 6;           // 0..47
    const int G = i & 63;
    const int tcl = min(t0 + (row >> 2), T_DIM - 1);
    const int ucl = min(u0 + (row & 3), U1 - 1);
    const float* er = hEnc + (size_t)(b * T_DIM + tcl) * K_INNER;
    const float* dr = hDec + (size_t)(b * U1 + ucl) * K_INNER;
    const int k = G << 3;
    float4 e0 = *(const float4*)(er + k);
    float4 e1 = *(const float4*)(er + k + 4);
    float4 d0 = *(const float4*)(dr + k);
    float4 d1 = *(const float4*)(dr + k + 4);
    uint2 pk = pk_fp8x8(tanh_fast(e0.x + d0.x), tanh_fast(e0.y + d0.y),
                        tanh_fast(e0.z + d0.z), tanh_fast(e0.w + d0.w),
                        tanh_fast(e1.x + d1.x), tanh_fast(e1.y + d1.y),
                        tanh_fast(e1.z + d1.z), tanh_fast(e1.w + d1.w));
    *(uint2*)&sh.X[row * XPITCH + (G << 3)] = pk;
  }

  // issue step-0 B loads: overlap the barrier (worst case drained there; then
  // the in-loop vmcnt(8) accounting is still correct -- it counts newest-8)
  LOADB(bv0, 0)
  __syncthreads();

  // A base: lane (l15,quad) holds row l15, k = ks4*128 + quad*32 + 0..31
  const uchar_t* aB = &sh.X[l15 * XPITCH + quad * 32];

  float sumexp[3][4], labelA[3][4], blankV[3][4];
#pragma unroll
  for (int i = 0; i < 3; ++i)
#pragma unroll
    for (int j = 0; j < 4; ++j) { sumexp[i][j] = 0.0f; labelA[i][j] = 0.0f; blankV[i][j] = 0.0f; }

  union AF { ifrag f; lfrag q[4]; };
  AF av0, av1, av2;                 // NAMED A fragments (24 VGPR)
  ffrag4 acc[3][4];

#define LDA(dst_, rb_, ks4_)                                                 \
  {                                                                          \
    const uchar_t* ap_ = aB + (rb_) * (16 * XPITCH) + (ks4_) * 128;          \
    dst_.q[0] = *(const lfrag*)(ap_);                                        \
    dst_.q[1] = *(const lfrag*)(ap_ + 8);                                    \
    dst_.q[2] = *(const lfrag*)(ap_ + 16);                                   \
    dst_.q[3] = *(const lfrag*)(ap_ + 24);                                   \
  }

#define MM1(rb_, cb_, AV, CUR)                                               \
  acc[rb_][cb_] = __builtin_amdgcn_mfma_scale_f32_16x16x128_f8f6f4(          \
      AV.f, CUR[cb_], acc[rb_][cb_], 0, 0, 0, 0x7f7f7f7f, 0, 0x7f7f7f7f);

  // one K-step: g = ct*4+ks4 (literal after the explicit 4-step sequence);
  // prefetch next step into NXT, consume CUR. vmcnt(8) = current 8 resident.
#define STEPK(g_, ks4_, CUR, NXT)                                            \
  {                                                                          \
    if ((g_) < 15) LOADB(NXT, (g_) + 1)                                      \
    LDA(av0, 0, ks4_)                                                        \
    LDA(av1, 1, ks4_)                                                        \
    LDA(av2, 2, ks4_)                                                        \
    if ((g_) < 15) { asm volatile("s_waitcnt vmcnt(8)" ::: "memory"); }      \
    else           { asm volatile("s_waitcnt vmcnt(0)" ::: "memory"); }      \
    __builtin_amdgcn_s_setprio(1);                                           \
    MM1(0, 0, av0, CUR) MM1(0, 1, av0, CUR) MM1(0, 2, av0, CUR) MM1(0, 3, av0, CUR) \
    MM1(1, 0, av1, CUR) MM1(1, 1, av1, CUR) MM1(1, 2, av1, CUR) MM1(1, 3, av1, CUR) \
    MM1(2, 0, av2, CUR) MM1(2, 1, av2, CUR) MM1(2, 2, av2, CUR) MM1(2, 3, av2, CUR) \
    __builtin_amdgcn_s_setprio(0);                                           \
  }

#pragma unroll
  for (int ct = 0; ct < 4; ++ct) {
    ffrag4 zero4 = {0.0f, 0.0f, 0.0f, 0.0f};
#pragma unroll
    for (int rb = 0; rb < 3; ++rb)
#pragma unroll
      for (int cb = 0; cb < 4; ++cb) acc[rb][cb] = zero4;

    STEPK(ct * 4 + 0, 0, bv0, bv1)
    STEPK(ct * 4 + 1, 1, bv1, bv0)
    STEPK(ct * 4 + 2, 2, bv0, bv1)
    STEPK(ct * 4 + 3, 3, bv1, bv0)

    // epilogue: acc = 16 x true logit (W2 scale); registers only + sb2
    // ds_reads (no vmem). Next ct's first B loads are already in flight ->
    // free latency cover.
#pragma unroll
    for (int cb = 0; cb < 4; ++cb) {
      const int v = ct * 256 + wave * 64 + cb * 16 + l15;
      const float bs = sb2[v];
#pragma unroll
      for (int rb = 0; rb < 3; ++rb)
#pragma unroll
        for (int reg = 0; reg < 4; ++reg) {
          float a = acc[rb][cb][reg];
          sumexp[rb][reg] += exp2f(fmaf(a, LOG2E16, bs));
          labelA[rb][reg] += (v == tokv[reg]) ? a : 0.0f;
        }
    }
    if (ct == 0 && wave == 0) {   // v==0 column lives on l15==0 lanes of cb 0
#pragma unroll
      for (int rb = 0; rb < 3; ++rb)
#pragma unroll
        for (int reg = 0; reg < 4; ++reg) blankV[rb][reg] = acc[rb][0][reg];
    }
  }
#undef STEPK
#undef MM1
#undef LDA
#undef LOADB

#pragma unroll
  for (int mask = 1; mask <= 8; mask <<= 1) {
#pragma unroll
    for (int rb = 0; rb < 3; ++rb)
#pragma unroll
      for (int reg = 0; reg < 4; ++reg) {
        sumexp[rb][reg] += __shfl_xor(sumexp[rb][reg], mask, 64);
        labelA[rb][reg] += __shfl_xor(labelA[rb][reg], mask, 64);
      }
  }

  __syncthreads();   // X reads done -> reuse union as red[]
  if (l15 == 0) {
#pragma unroll
    for (int rb = 0; rb < 3; ++rb)
#pragma unroll
      for (int reg = 0; reg < 4; ++reg) {
        int row = rb * 16 + quad * 4 + reg;
        sh.red[wave][row][0] = sumexp[rb][reg];
        sh.red[wave][row][1] = blankV[rb][reg];
        sh.red[wave][row][2] = labelA[rb][reg];
      }
  }
  __syncthreads();
  if (tid < ROWS) {
    float S  = sh.red[0][tid][0] + sh.red[1][tid][0] + sh.red[2][tid][0] + sh.red[3][tid][0];
    float Bl = sh.red[0][tid][1];
    float Lb = sh.red[0][tid][2] + sh.red[1][tid][2] + sh.red[2][tid][2] + sh.red[3][tid][2];
    int t = t0 + (tid >> 2);
    int u = u0 + (tid & 3);
    if (t < T_DIM && u < U1) {
      float lse2 = __log2f(S);                 // S = sum(exp(true logit))
      int tok = (u < U_DIM) ? tokens[b * U_DIM + u] : 0;
      int d = t + u;
      size_t idx = (((size_t)b * ND + d) * 128 + u) * 2;
      pD[idx]     = fmaf(Bl, LOG2E16, sb2[0])   - lse2;   // blank
      pD[idx + 1] = fmaf(Lb, LOG2E16, sb2[tok]) - lse2;   // label
    }
  }
}

// ---------------- RNNT DP, log2 domain, LDS-staged triple-buffered chunks.
// r9 residual (~100us, ~330cyc/step): per-step ds_read latency sat on the serial
// chain. Fix: batch all 8 q-reads of a chunk into registers (unrolled float4
// qv[8]) before the 8-step chain -- LDS latency paid once per chunk.
__global__ __launch_bounds__(256)
void dp_kernel(const float* __restrict__ pD,
               const int* __restrict__ outLen, const int* __restrict__ tokLen,
               float* __restrict__ outLoss)
{
  __shared__ __align__(16) float sD[4][3][CHUNK * 256];   // 96 KB triple buffer
  __shared__ float llsh[B_DIM];
  const int tid = threadIdx.x;
  const int wv = tid >> 6;                  // wave = batch
  const int lane = tid & 63;
  const float* src = pD + (size_t)wv * ND * 256;
  const int tIdx = outLen[wv] - 1;
  const int uIdx = tokLen[wv];
  const int dStar = tIdx + uIdx;
  const float NEG = -1e30f;
  const float blkStar = src[((size_t)dStar * 128 + uIdx) * 2];

  float aE = (lane == 0) ? 0.0f : NEG;      // log2 domain
  float aO = NEG;
  float ll2 = 0.0f;
  if (dStar == 0 && lane == 0) ll2 = blkStar;

  const int uE = 2 * lane;

#define ISSUE(c, buf)                                                         \
  {                                                                           \
    const float* g_ = src + (size_t)(c) * (CHUNK * 256);                      \
    float* l_ = &sD[wv][(buf)][0];                                            \
    _Pragma("unroll")                                                         \
    for (int j_ = 0; j_ < CHUNK; ++j_)                                        \
      __builtin_amdgcn_global_load_lds(                                       \
        (const __attribute__((address_space(1))) void*)(g_ + j_ * 256 + lane * 4), \
        (__attribute__((address_space(3))) void*)(l_ + j_ * 256), 16, 0, 0);  \
  }

  ISSUE(0, 0)
  ISSUE(1, 1)
#pragma unroll 1
  for (int c = 0; c < 38; ++c) {
    { const int nc = c + 2; const int cc = nc <= 37 ? nc : 37; ISSUE(cc, nc % 3) }
    asm volatile("s_waitcnt vmcnt(16)" ::: "memory");   // chunk c resident
    const float* buf = &sD[wv][c % 3][0];
    float4 qv[CHUNK];
#pragma unroll
    for (int j = 0; j < CHUNK; ++j)
      qv[j] = *(const float4*)&buf[j * 256 + uE * 2];
#pragma unroll
    for (int j = 0; j < CHUNK; ++j) {
      const int d = c * CHUNK + 1 + j;
      float4 q = qv[j];
      // q = (B[uE], L[uE], B[uE+1], L[uE+1]) at source diag d-1
      float aO_up = dpp_up1(aO, NEG);
      float labUp = dpp_up1(q.w, NEG);                // L[uE-1] @ d-1
      // uE cell
      float bt0 = aE + q.x, lt0 = aO_up + labUp;
      float mx0 = fmaxf(bt0, lt0), mn0 = fminf(bt0, lt0);
      float r0 = mx0 + __log2f(1.0f + exp2f(mn0 - mx0));
      int te = d - uE;
      float nE = ((uE <= U_DIM) && (te >= 0) && (te < T_DIM)) ? r0 : NEG;
      // uO cell
      float bt1 = aO + q.z, lt1 = aE + q.y;
      float mx1 = fmaxf(bt1, lt1), mn1 = fminf(bt1, lt1);
      float r1 = mx1 + __log2f(1.0f + exp2f(mn1 - mx1));
      int to = te - 1;
      float nO = ((uE + 1 <= U_DIM) && (to >= 0) && (to < T_DIM)) ? r1 : NEG;
      aE = nE; aO = nO;
      if (d == dStar) {
        if (uIdx == uE)          ll2 = nE + blkStar;
        else if (uIdx == uE + 1) ll2 = nO + blkStar;
      }
    }
  }
#undef ISSUE

#pragma unroll
  for (int mask = 1; mask < 64; mask <<= 1) ll2 += __shfl_xor(ll2, mask, 64);
  if (lane == 0) llsh[wv] = ll2;
  __syncthreads();
  if (tid == 0)
    outLoss[0] = -(llsh[0] + llsh[1] + llsh[2] + llsh[3]) * 0.25f * LN2;
}

// ---------------- launch
extern "C" void kernel_launch(void* const* d_in, const int* in_sizes, int n_in,
                              void* d_out, int out_size, void* d_ws, size_t ws_size,
                              hipStream_t stream)
{
  const float* enc    = (const float*)d_in[0];
  const float* dec    = (const float*)d_in[1];
  const int*   tokens = (const int*)d_in[2];
  const int*   outLen = (const int*)d_in[3];
  const int*   tokLen = (const int*)d_in[4];
  const float* W1     = (const float*)d_in[5];
  const float* b1     = (const float*)d_in[6];
  const float* W2     = (const float*)d_in[7];
  const float* b2     = (const float*)d_in[8];
  float* out = (float*)d_out;

  char* ws = (char*)d_ws;
  float*   hEnc = (float*)(ws + 0);           // 800*512*4     = 1,638,400
  float*   hDec = (float*)(ws + 1638400);     // 404*512*4     =   827,392
  uchar_t* W2f8 = (uchar_t*)(ws + 2465792);   // 256 regions*2048 = 524,288 (16-aligned)
  float*   pD   = (float*)(ws + 2990080);     // 4*300*128*2*4 = 1,228,800
                                              // + 16KB tail pad for dp chunk-37 overread

  prep_kernel<<<dim3(215), dim3(512), 0, stream>>>(enc, dec, W1, W2, b1, hEnc, hDec, W2f8);
  joint_kernel<<<dim3(26, 17, B_DIM), dim3(256), 0, stream>>>(hEnc, hDec, W2f8, b2, tokens, pD);
  dp_kernel<<<dim3(1), dim3(256), 0, stream>>>(pD, outLen, tokLen, out);
}

// Round 11
// 231.583 us; speedup vs baseline: 1.4361x; 1.0502x over previous
//
#include <hip/hip_runtime.h>
#include <hip/hip_bf16.h>

#define T_DIM 200
#define U_DIM 100
#define U1    101
#define H_DIM 320
#define K_INNER 512
#define V_DIM 1000
#define B_DIM 4
#define ND 300            // diagonals d = t+u in [0, 299]
#define ROWS 48           // 12 t x 4 u per block (R2-proven tile)
#define XPITCH 520        // 512 fp8 + 8B pad: conflict-free + imm-offset addressable
#define CHUNK 8           // dp: diagonals per LDS chunk

typedef unsigned short ushort_t;
typedef unsigned char uchar_t;
typedef unsigned int uint32;
typedef long lfrag;       // 8 x fp8 = 2 VGPRs

typedef float ffrag4 __attribute__((ext_vector_type(4)));
typedef int   ifrag  __attribute__((ext_vector_type(8)));   // 32 x fp8 = 8 VGPRs

#define LOG2E   1.4426950408889634f
#define LOG2E16 (1.4426950408889634f * 0.0625f)   // LOG2E/16 (W2 packed with x16 scale)
#define LN2     0.6931471805599453f

__device__ __forceinline__ float tanh_fast(float x) {
  float e = __expf(2.0f * x);                 // inf-safe: e=inf -> 1, e=0 -> -1
  return 1.0f - __fdividef(2.0f, e + 1.0f);
}

__device__ __forceinline__ uint2 pk_fp8x8(float t0, float t1, float t2, float t3,
                                          float t4, float t5, float t6, float t7) {
  uint2 r;
  r.x = (uint32)__builtin_amdgcn_cvt_pk_fp8_f32(t0, t1, 0, false);
  r.x = (uint32)__builtin_amdgcn_cvt_pk_fp8_f32(t2, t3, (int)r.x, true);
  r.y = (uint32)__builtin_amdgcn_cvt_pk_fp8_f32(t4, t5, 0, false);
  r.y = (uint32)__builtin_amdgcn_cvt_pk_fp8_f32(t6, t7, (int)r.y, true);
  return r;
}

// lane i <- lane i-1 (wave_shr:1 DPP, VALU-speed); invalid lane 0 gets `oldv`
__device__ __forceinline__ float dpp_up1(float v, float oldv) {
  return __int_as_float(__builtin_amdgcn_update_dpp(
      __float_as_int(oldv), __float_as_int(v), 0x138, 0xf, 0xf, false));
}

// ---------------- fused prep (r18: projection split 8->4 rows/block):
//   blocks [0,200):   h_enc projection (4 rows each) -- b1 FOLDED IN:
//                     hEnc := enc@W1[:H] + b1
//   blocks [200,301): h_dec projection (4 rows each)
//   blocks [301,365): W2 transpose-pack (x16 scale), unchanged layout
// Rationale: at 215 blocks the proj grid was 0.84 blocks/CU (half the CUs
// idle, ~2 waves/SIMD) with an 80-iter L2-latency chain on the W1 column
// walk. 365 blocks -> ~1.4 blocks/CU, 2x the latency-hiding waves; per-block
// work halves. Same memory pattern (W1 L2-resident), same store layout.
__global__ __launch_bounds__(512)
void prep_kernel(const float* __restrict__ enc, const float* __restrict__ dec,
                 const float* __restrict__ W1, const float* __restrict__ W2,
                 const float* __restrict__ b1,
                 float* __restrict__ hEnc, float* __restrict__ hDec,
                 uchar_t* __restrict__ W2f8)
{
  __shared__ union { float sIn[4][H_DIM]; float sW[8][1024]; } sh;
  const int tid = threadIdx.x;
  const int blk = blockIdx.x;

  if (blk < 301) {
    const float* inp; float* outp; int nRows, rowOff, b0;
    if (blk < 200) { inp = enc; outp = hEnc; nRows = B_DIM * T_DIM; rowOff = 0;     b0 = blk; }
    else           { inp = dec; outp = hDec; nRows = B_DIM * U1;    rowOff = H_DIM; b0 = blk - 200; }
    const int r0 = b0 * 4;
    for (int i = tid; i < 4 * H_DIM; i += 512) {
      int r = i / H_DIM, k = i - r * H_DIM;
      int rr = r0 + r;
      sh.sIn[r][k] = (rr < nRows) ? inp[(size_t)rr * H_DIM + k] : 0.0f;
    }
    __syncthreads();
    const int c = tid;  // 0..511
    float acc[4];
#pragma unroll
    for (int r = 0; r < 4; ++r) acc[r] = 0.0f;
    const float* Wp = W1 + (size_t)rowOff * K_INNER + c;
    for (int k = 0; k < H_DIM; k += 4) {
      float w0 = Wp[(size_t)(k + 0) * K_INNER];
      float w1 = Wp[(size_t)(k + 1) * K_INNER];
      float w2 = Wp[(size_t)(k + 2) * K_INNER];
      float w3 = Wp[(size_t)(k + 3) * K_INNER];
#pragma unroll
      for (int r = 0; r < 4; ++r) {
        float4 s = *(const float4*)&sh.sIn[r][k];
        acc[r] = fmaf(s.w, w3, fmaf(s.z, w2, fmaf(s.y, w1, fmaf(s.x, w0, acc[r]))));
      }
    }
    const float bb = (rowOff == 0) ? b1[c] : 0.0f;   // fold b1 into hEnc only
#pragma unroll
    for (int r = 0; r < 4; ++r) {
      int rr = r0 + r;
      if (rr < nRows) outp[(size_t)rr * K_INNER + c] = acc[r] + bb;
    }
  } else {
    // W2 pack: kchunk kc covers k in [kc*8, kc*8+8); LDS transpose; x16 scale
    // (raw |w| <= 0.045 sits in e4m3's denormal zone; x16 -> +-0.71, normal)
    const int kc = blk - 301;
    for (int i = tid; i < 8 * 1024; i += 512) {
      int r = i >> 10, n = i & 1023;
      sh.sW[r][n] = (n < V_DIM) ? W2[(size_t)(kc * 8 + r) * V_DIM + n] : 0.0f;
    }
    __syncthreads();
    // k = kc*8 + r:  ks4 = k>>7, quad = (k>>5)&3, i = k&31, part = i>>4, io = i&15
    const int ks4 = kc >> 4, qd = (kc >> 2) & 3, part = (kc >> 1) & 1, io = (kc & 1) * 8;
#pragma unroll
    for (int h = 0; h < 2; ++h) {
      int n = tid + h * 512;
      uint2 pk = pk_fp8x8(sh.sW[0][n] * 16.f, sh.sW[1][n] * 16.f,
                          sh.sW[2][n] * 16.f, sh.sW[3][n] * 16.f,
                          sh.sW[4][n] * 16.f, sh.sW[5][n] * 16.f,
                          sh.sW[6][n] * 16.f, sh.sW[7][n] * 16.f);
      const int ct = n >> 8, w = (n >> 6) & 3, cb = (n >> 4) & 3, l15 = n & 15;
      const int R = ct * 64 + ks4 * 16 + w * 4 + cb;
      const size_t off = (size_t)R * 2048 + part * 1024 + (qd * 16 + l15) * 16 + io;
      *(uint2*)&W2f8[off] = pk;
    }
  }
}

// ---------------- fused joint, MX-scaled fp8 (16x16x128, unity e8m0 scales),
// 48-row tile, (256,2) -- BYTE-IDENTICAL to R9 (95.6us, VGPR 112, no scratch).
// R9 falsified the 170-reg 3-wave model (160 total still 2 waves/SIMD; real
// boundary is coarser-quantized, <=~150). Occupancy chase CLOSED; this kernel
// is the session's stable optimum for the joint stage.
__global__ __launch_bounds__(256, 2)
void joint_kernel(const float* __restrict__ hEnc, const float* __restrict__ hDec,
                  const uchar_t* __restrict__ W2f8,
                  const float* __restrict__ b2, const int* __restrict__ tokens,
                  float* __restrict__ pD)
{
  __shared__ union SU {
    uchar_t X[ROWS * XPITCH];     // 48 x 520 = 24,960 B
    float red[4][ROWS][4];
  } sh;
  __shared__ float sb2[1024];     // b2 * LOG2E (padded with -1e30)

  const int tid = threadIdx.x;
  const int b  = blockIdx.z;
  const int t0 = blockIdx.y * 12;   // 17 blocks cover 200 (writes guarded)
  const int u0 = blockIdx.x * 4;    // 26 blocks cover 104 >= 101
  const int wave = tid >> 6;
  const int lane = tid & 63;
  const int l15 = lane & 15;
  const int quad = lane >> 4;

  // per-wave global B base: region R = g*16 + wave*4 + cb, lane-major 16B.
  // All offsets are compile-time constants folded per unrolled step.
  const uchar_t* gB = W2f8 + (size_t)wave * 8192 + (size_t)lane * 16;
  ifrag bv0[4], bv1[4];             // NAMED B double-buffers (64 VGPR)

#define LOADB(buf_, g_)                                                        \
  {                                                                            \
    *(int4*)&buf_[0]         = *(const int4*)(gB + (size_t)((g_)*16 + 0) * 2048);          \
    *(((int4*)&buf_[0]) + 1) = *(const int4*)(gB + (size_t)((g_)*16 + 0) * 2048 + 1024);   \
    *(int4*)&buf_[1]         = *(const int4*)(gB + (size_t)((g_)*16 + 1) * 2048);          \
    *(((int4*)&buf_[1]) + 1) = *(const int4*)(gB + (size_t)((g_)*16 + 1) * 2048 + 1024);   \
    *(int4*)&buf_[2]         = *(const int4*)(gB + (size_t)((g_)*16 + 2) * 2048);          \
    *(((int4*)&buf_[2]) + 1) = *(const int4*)(gB + (size_t)((g_)*16 + 2) * 2048 + 1024);   \
    *(int4*)&buf_[3]         = *(const int4*)(gB + (size_t)((g_)*16 + 3) * 2048);          \
    *(((int4*)&buf_[3]) + 1) = *(const int4*)(gB + (size_t)((g_)*16 + 3) * 2048 + 1024);   \
  }

  // tokens to regs (retire at the staging barrier)
  int tokv[4];
#pragma unroll
  for (int j = 0; j < 4; ++j)
    tokv[j] = (u0 + j < U_DIM) ? tokens[b * U_DIM + u0 + j] : -1;

  // b2 (scaled) -> LDS table (frees 16 VGPR vs the b2s register array)
  for (int i = tid; i < 1024; i += 256)
    sb2[i] = (i < V_DIM) ? b2[i] * LOG2E : -1e30f;

  // ---- X staging: per pass a wave owns one row; G = lane -> conflict-free
  // (hEnc already contains +b1)
  for (int i = tid; i < ROWS * 64; i += 256) {
    const int row = i >> 6;           // 0..47
    const int G = i & 63;
    const int tcl = min(t0 + (row >> 2), T_DIM - 1);
    const int ucl = min(u0 + (row & 3), U1 - 1);
    const float* er = hEnc + (size_t)(b * T_DIM + tcl) * K_INNER;
    const float* dr = hDec + (size_t)(b * U1 + ucl) * K_INNER;
    const int k = G << 3;
    float4 e0 = *(const float4*)(er + k);
    float4 e1 = *(const float4*)(er + k + 4);
    float4 d0 = *(const float4*)(dr + k);
    float4 d1 = *(const float4*)(dr + k + 4);
    uint2 pk = pk_fp8x8(tanh_fast(e0.x + d0.x), tanh_fast(e0.y + d0.y),
                        tanh_fast(e0.z + d0.z), tanh_fast(e0.w + d0.w),
                        tanh_fast(e1.x + d1.x), tanh_fast(e1.y + d1.y),
                        tanh_fast(e1.z + d1.z), tanh_fast(e1.w + d1.w));
    *(uint2*)&sh.X[row * XPITCH + (G << 3)] = pk;
  }

  // issue step-0 B loads: overlap the barrier (worst case drained there; then
  // the in-loop vmcnt(8) accounting is still correct -- it counts newest-8)
  LOADB(bv0, 0)
  __syncthreads();

  // A base: lane (l15,quad) holds row l15, k = ks4*128 + quad*32 + 0..31
  const uchar_t* aB = &sh.X[l15 * XPITCH + quad * 32];

  float sumexp[3][4], labelA[3][4], blankV[3][4];
#pragma unroll
  for (int i = 0; i < 3; ++i)
#pragma unroll
    for (int j = 0; j < 4; ++j) { sumexp[i][j] = 0.0f; labelA[i][j] = 0.0f; blankV[i][j] = 0.0f; }

  union AF { ifrag f; lfrag q[4]; };
  AF av0, av1, av2;                 // NAMED A fragments (24 VGPR)
  ffrag4 acc[3][4];

#define LDA(dst_, rb_, ks4_)                                                 \
  {                                                                          \
    const uchar_t* ap_ = aB + (rb_) * (16 * XPITCH) + (ks4_) * 128;          \
    dst_.q[0] = *(const lfrag*)(ap_);                                        \
    dst_.q[1] = *(const lfrag*)(ap_ + 8);                                    \
    dst_.q[2] = *(const lfrag*)(ap_ + 16);                                   \
    dst_.q[3] = *(const lfrag*)(ap_ + 24);                                   \
  }

#define MM1(rb_, cb_, AV, CUR)                                               \
  acc[rb_][cb_] = __builtin_amdgcn_mfma_scale_f32_16x16x128_f8f6f4(          \
      AV.f, CUR[cb_], acc[rb_][cb_], 0, 0, 0, 0x7f7f7f7f, 0, 0x7f7f7f7f);

  // one K-step: g = ct*4+ks4 (literal after the explicit 4-step sequence);
  // prefetch next step into NXT, consume CUR. vmcnt(8) = current 8 resident.
#define STEPK(g_, ks4_, CUR, NXT)                                            \
  {                                                                          \
    if ((g_) < 15) LOADB(NXT, (g_) + 1)                                      \
    LDA(av0, 0, ks4_)                                                        \
    LDA(av1, 1, ks4_)                                                        \
    LDA(av2, 2, ks4_)                                                        \
    if ((g_) < 15) { asm volatile("s_waitcnt vmcnt(8)" ::: "memory"); }      \
    else           { asm volatile("s_waitcnt vmcnt(0)" ::: "memory"); }      \
    __builtin_amdgcn_s_setprio(1);                                           \
    MM1(0, 0, av0, CUR) MM1(0, 1, av0, CUR) MM1(0, 2, av0, CUR) MM1(0, 3, av0, CUR) \
    MM1(1, 0, av1, CUR) MM1(1, 1, av1, CUR) MM1(1, 2, av1, CUR) MM1(1, 3, av1, CUR) \
    MM1(2, 0, av2, CUR) MM1(2, 1, av2, CUR) MM1(2, 2, av2, CUR) MM1(2, 3, av2, CUR) \
    __builtin_amdgcn_s_setprio(0);                                           \
  }

#pragma unroll
  for (int ct = 0; ct < 4; ++ct) {
    ffrag4 zero4 = {0.0f, 0.0f, 0.0f, 0.0f};
#pragma unroll
    for (int rb = 0; rb < 3; ++rb)
#pragma unroll
      for (int cb = 0; cb < 4; ++cb) acc[rb][cb] = zero4;

    STEPK(ct * 4 + 0, 0, bv0, bv1)
    STEPK(ct * 4 + 1, 1, bv1, bv0)
    STEPK(ct * 4 + 2, 2, bv0, bv1)
    STEPK(ct * 4 + 3, 3, bv1, bv0)

    // epilogue: acc = 16 x true logit (W2 scale); registers only + sb2
    // ds_reads (no vmem). Next ct's first B loads are already in flight ->
    // free latency cover.
#pragma unroll
    for (int cb = 0; cb < 4; ++cb) {
      const int v = ct * 256 + wave * 64 + cb * 16 + l15;
      const float bs = sb2[v];
#pragma unroll
      for (int rb = 0; rb < 3; ++rb)
#pragma unroll
        for (int reg = 0; reg < 4; ++reg) {
          float a = acc[rb][cb][reg];
          sumexp[rb][reg] += exp2f(fmaf(a, LOG2E16, bs));
          labelA[rb][reg] += (v == tokv[reg]) ? a : 0.0f;
        }
    }
    if (ct == 0 && wave == 0) {   // v==0 column lives on l15==0 lanes of cb 0
#pragma unroll
      for (int rb = 0; rb < 3; ++rb)
#pragma unroll
        for (int reg = 0; reg < 4; ++reg) blankV[rb][reg] = acc[rb][0][reg];
    }
  }
#undef STEPK
#undef MM1
#undef LDA
#undef LOADB

#pragma unroll
  for (int mask = 1; mask <= 8; mask <<= 1) {
#pragma unroll
    for (int rb = 0; rb < 3; ++rb)
#pragma unroll
      for (int reg = 0; reg < 4; ++reg) {
        sumexp[rb][reg] += __shfl_xor(sumexp[rb][reg], mask, 64);
        labelA[rb][reg] += __shfl_xor(labelA[rb][reg], mask, 64);
      }
  }

  __syncthreads();   // X reads done -> reuse union as red[]
  if (l15 == 0) {
#pragma unroll
    for (int rb = 0; rb < 3; ++rb)
#pragma unroll
      for (int reg = 0; reg < 4; ++reg) {
        int row = rb * 16 + quad * 4 + reg;
        sh.red[wave][row][0] = sumexp[rb][reg];
        sh.red[wave][row][1] = blankV[rb][reg];
        sh.red[wave][row][2] = labelA[rb][reg];
      }
  }
  __syncthreads();
  if (tid < ROWS) {
    float S  = sh.red[0][tid][0] + sh.red[1][tid][0] + sh.red[2][tid][0] + sh.red[3][tid][0];
    float Bl = sh.red[0][tid][1];
    float Lb = sh.red[0][tid][2] + sh.red[1][tid][2] + sh.red[2][tid][2] + sh.red[3][tid][2];
    int t = t0 + (tid >> 2);
    int u = u0 + (tid & 3);
    if (t < T_DIM && u < U1) {
      float lse2 = __log2f(S);                 // S = sum(exp(true logit))
      int tok = (u < U_DIM) ? tokens[b * U_DIM + u] : 0;
      int d = t + u;
      size_t idx = (((size_t)b * ND + d) * 128 + u) * 2;
      pD[idx]     = fmaf(Bl, LOG2E16, sb2[0])   - lse2;   // blank
      pD[idx + 1] = fmaf(Lb, LOG2E16, sb2[tok]) - lse2;   // label
    }
  }
}

// ---------------- RNNT DP, log2 domain, LDS-staged triple-buffered chunks --
// BYTE-IDENTICAL to R9 (proven; the R10 128KB quad-buffer variant is shelved
// until the container-failure cause is known: 128KB static LDS was the only
// untested novelty in R10's failing build).
__global__ __launch_bounds__(256)
void dp_kernel(const float* __restrict__ pD,
               const int* __restrict__ outLen, const int* __restrict__ tokLen,
               float* __restrict__ outLoss)
{
  __shared__ __align__(16) float sD[4][3][CHUNK * 256];   // 96 KB triple buffer
  __shared__ float llsh[B_DIM];
  const int tid = threadIdx.x;
  const int wv = tid >> 6;                  // wave = batch
  const int lane = tid & 63;
  const float* src = pD + (size_t)wv * ND * 256;
  const int tIdx = outLen[wv] - 1;
  const int uIdx = tokLen[wv];
  const int dStar = tIdx + uIdx;
  const float NEG = -1e30f;
  const float blkStar = src[((size_t)dStar * 128 + uIdx) * 2];

  float aE = (lane == 0) ? 0.0f : NEG;      // log2 domain
  float aO = NEG;
  float ll2 = 0.0f;
  if (dStar == 0 && lane == 0) ll2 = blkStar;

  const int uE = 2 * lane;

#define ISSUE(c, buf)                                                         \
  {                                                                           \
    const float* g_ = src + (size_t)(c) * (CHUNK * 256);                      \
    float* l_ = &sD[wv][(buf)][0];                                            \
    _Pragma("unroll")                                                         \
    for (int j_ = 0; j_ < CHUNK; ++j_)                                        \
      __builtin_amdgcn_global_load_lds(                                       \
        (const __attribute__((address_space(1))) void*)(g_ + j_ * 256 + lane * 4), \
        (__attribute__((address_space(3))) void*)(l_ + j_ * 256), 16, 0, 0);  \
  }

  ISSUE(0, 0)
  ISSUE(1, 1)
#pragma unroll 1
  for (int c = 0; c < 38; ++c) {
    { const int nc = c + 2; const int cc = nc <= 37 ? nc : 37; ISSUE(cc, nc % 3) }
    asm volatile("s_waitcnt vmcnt(16)" ::: "memory");   // chunk c resident
    const float* buf = &sD[wv][c % 3][0];
    float4 qv[CHUNK];
#pragma unroll
    for (int j = 0; j < CHUNK; ++j)
      qv[j] = *(const float4*)&buf[j * 256 + uE * 2];
#pragma unroll
    for (int j = 0; j < CHUNK; ++j) {
      const int d = c * CHUNK + 1 + j;
      float4 q = qv[j];
      // q = (B[uE], L[uE], B[uE+1], L[uE+1]) at source diag d-1
      float aO_up = dpp_up1(aO, NEG);
      float labUp = dpp_up1(q.w, NEG);                // L[uE-1] @ d-1
      // uE cell
      float bt0 = aE + q.x, lt0 = aO_up + labUp;
      float mx0 = fmaxf(bt0, lt0), mn0 = fminf(bt0, lt0);
      float r0 = mx0 + __log2f(1.0f + exp2f(mn0 - mx0));
      int te = d - uE;
      float nE = ((uE <= U_DIM) && (te >= 0) && (te < T_DIM)) ? r0 : NEG;
      // uO cell
      float bt1 = aO + q.z, lt1 = aE + q.y;
      float mx1 = fmaxf(bt1, lt1), mn1 = fminf(bt1, lt1);
      float r1 = mx1 + __log2f(1.0f + exp2f(mn1 - mx1));
      int to = te - 1;
      float nO = ((uE + 1 <= U_DIM) && (to >= 0) && (to < T_DIM)) ? r1 : NEG;
      aE = nE; aO = nO;
      if (d == dStar) {
        if (uIdx == uE)          ll2 = nE + blkStar;
        else if (uIdx == uE + 1) ll2 = nO + blkStar;
      }
    }
  }
#undef ISSUE

#pragma unroll
  for (int mask = 1; mask < 64; mask <<= 1) ll2 += __shfl_xor(ll2, mask, 64);
  if (lane == 0) llsh[wv] = ll2;
  __syncthreads();
  if (tid == 0)
    outLoss[0] = -(llsh[0] + llsh[1] + llsh[2] + llsh[3]) * 0.25f * LN2;
}

// ---------------- launch
extern "C" void kernel_launch(void* const* d_in, const int* in_sizes, int n_in,
                              void* d_out, int out_size, void* d_ws, size_t ws_size,
                              hipStream_t stream)
{
  const float* enc    = (const float*)d_in[0];
  const float* dec    = (const float*)d_in[1];
  const int*   tokens = (const int*)d_in[2];
  const int*   outLen = (const int*)d_in[3];
  const int*   tokLen = (const int*)d_in[4];
  const float* W1     = (const float*)d_in[5];
  const float* b1     = (const float*)d_in[6];
  const float* W2     = (const float*)d_in[7];
  const float* b2     = (const float*)d_in[8];
  float* out = (float*)d_out;

  char* ws = (char*)d_ws;
  float*   hEnc = (float*)(ws + 0);           // 800*512*4     = 1,638,400
  float*   hDec = (float*)(ws + 1638400);     // 404*512*4     =   827,392
  uchar_t* W2f8 = (uchar_t*)(ws + 2465792);   // 256 regions*2048 = 524,288 (16-aligned)
  float*   pD   = (float*)(ws + 2990080);     // 4*300*128*2*4 = 1,228,800
                                              // + 16KB tail pad for dp chunk-37 overread

  prep_kernel<<<dim3(365), dim3(512), 0, stream>>>(enc, dec, W1, W2, b1, hEnc, hDec, W2f8);
  joint_kernel<<<dim3(26, 17, B_DIM), dim3(256), 0, stream>>>(hEnc, hDec, W2f8, b2, tokens, pD);
  dp_kernel<<<dim3(1), dim3(256), 0, stream>>>(pD, outLen, tokLen, out);
}

// Round 12
// 227.884 us; speedup vs baseline: 1.4594x; 1.0162x over previous
//
#include <hip/hip_runtime.h>
#include <hip/hip_bf16.h>

#define T_DIM 200
#define U_DIM 100
#define U1    101
#define H_DIM 320
#define K_INNER 512
#define V_DIM 1000
#define B_DIM 4
#define ND 300            // diagonals d = t+u in [0, 299]
#define ROWS 48           // 12 t x 4 u per block (R2-proven tile)
#define XPITCH 520        // 512 fp8 + 8B pad: conflict-free + imm-offset addressable
#define CHUNK 8           // dp: diagonals per LDS chunk

typedef unsigned short ushort_t;
typedef unsigned char uchar_t;
typedef unsigned int uint32;
typedef long lfrag;       // 8 x fp8 = 2 VGPRs

typedef float ffrag4 __attribute__((ext_vector_type(4)));
typedef int   ifrag  __attribute__((ext_vector_type(8)));   // 32 x fp8 = 8 VGPRs

#define LOG2E   1.4426950408889634f
#define LOG2E16 (1.4426950408889634f * 0.0625f)   // LOG2E/16 (W2 packed with x16 scale)
#define LN2     0.6931471805599453f

__device__ __forceinline__ float tanh_fast(float x) {
  float e = __expf(2.0f * x);                 // inf-safe: e=inf -> 1, e=0 -> -1
  return 1.0f - __fdividef(2.0f, e + 1.0f);
}

__device__ __forceinline__ uint2 pk_fp8x8(float t0, float t1, float t2, float t3,
                                          float t4, float t5, float t6, float t7) {
  uint2 r;
  r.x = (uint32)__builtin_amdgcn_cvt_pk_fp8_f32(t0, t1, 0, false);
  r.x = (uint32)__builtin_amdgcn_cvt_pk_fp8_f32(t2, t3, (int)r.x, true);
  r.y = (uint32)__builtin_amdgcn_cvt_pk_fp8_f32(t4, t5, 0, false);
  r.y = (uint32)__builtin_amdgcn_cvt_pk_fp8_f32(t6, t7, (int)r.y, true);
  return r;
}

// lane i <- lane i-1 (wave_shr:1 DPP, VALU-speed); invalid lane 0 gets `oldv`
__device__ __forceinline__ float dpp_up1(float v, float oldv) {
  return __int_as_float(__builtin_amdgcn_update_dpp(
      __float_as_int(oldv), __float_as_int(v), 0x138, 0xf, 0xf, false));
}

// ---------------- fused prep (r19: projection split 4->2 rows/block):
//   blocks [0,400):   h_enc projection (2 rows each) -- b1 FOLDED IN:
//                     hEnc := enc@W1[:H] + b1
//   blocks [400,602): h_dec projection (2 rows each)
//   blocks [602,666): W2 transpose-pack (x16 scale), unchanged layout
// R11 measured the 8->4 split at -34us non-joint (latency-hiding theory
// confirmed). 4->2 doubles the wave pool again (~2.6 blocks/CU, ~5 waves/
// SIMD); the per-thread W1 column-walk chain (320 stride-512 coalesced
// loads, the latency-bound part) is unchanged, per-thread FMA work halves.
__global__ __launch_bounds__(512)
void prep_kernel(const float* __restrict__ enc, const float* __restrict__ dec,
                 const float* __restrict__ W1, const float* __restrict__ W2,
                 const float* __restrict__ b1,
                 float* __restrict__ hEnc, float* __restrict__ hDec,
                 uchar_t* __restrict__ W2f8)
{
  __shared__ union { float sIn[2][H_DIM]; float sW[8][1024]; } sh;
  const int tid = threadIdx.x;
  const int blk = blockIdx.x;

  if (blk < 602) {
    const float* inp; float* outp; int nRows, rowOff, b0;
    if (blk < 400) { inp = enc; outp = hEnc; nRows = B_DIM * T_DIM; rowOff = 0;     b0 = blk; }
    else           { inp = dec; outp = hDec; nRows = B_DIM * U1;    rowOff = H_DIM; b0 = blk - 400; }
    const int r0 = b0 * 2;
    for (int i = tid; i < 2 * H_DIM; i += 512) {
      int r = i / H_DIM, k = i - r * H_DIM;
      int rr = r0 + r;
      sh.sIn[r][k] = (rr < nRows) ? inp[(size_t)rr * H_DIM + k] : 0.0f;
    }
    __syncthreads();
    const int c = tid;  // 0..511
    float acc[2];
#pragma unroll
    for (int r = 0; r < 2; ++r) acc[r] = 0.0f;
    const float* Wp = W1 + (size_t)rowOff * K_INNER + c;
    for (int k = 0; k < H_DIM; k += 4) {
      float w0 = Wp[(size_t)(k + 0) * K_INNER];
      float w1 = Wp[(size_t)(k + 1) * K_INNER];
      float w2 = Wp[(size_t)(k + 2) * K_INNER];
      float w3 = Wp[(size_t)(k + 3) * K_INNER];
#pragma unroll
      for (int r = 0; r < 2; ++r) {
        float4 s = *(const float4*)&sh.sIn[r][k];
        acc[r] = fmaf(s.w, w3, fmaf(s.z, w2, fmaf(s.y, w1, fmaf(s.x, w0, acc[r]))));
      }
    }
    const float bb = (rowOff == 0) ? b1[c] : 0.0f;   // fold b1 into hEnc only
#pragma unroll
    for (int r = 0; r < 2; ++r) {
      int rr = r0 + r;
      if (rr < nRows) outp[(size_t)rr * K_INNER + c] = acc[r] + bb;
    }
  } else {
    // W2 pack: kchunk kc covers k in [kc*8, kc*8+8); LDS transpose; x16 scale
    // (raw |w| <= 0.045 sits in e4m3's denormal zone; x16 -> +-0.71, normal)
    const int kc = blk - 602;
    for (int i = tid; i < 8 * 1024; i += 512) {
      int r = i >> 10, n = i & 1023;
      sh.sW[r][n] = (n < V_DIM) ? W2[(size_t)(kc * 8 + r) * V_DIM + n] : 0.0f;
    }
    __syncthreads();
    // k = kc*8 + r:  ks4 = k>>7, quad = (k>>5)&3, i = k&31, part = i>>4, io = i&15
    const int ks4 = kc >> 4, qd = (kc >> 2) & 3, part = (kc >> 1) & 1, io = (kc & 1) * 8;
#pragma unroll
    for (int h = 0; h < 2; ++h) {
      int n = tid + h * 512;
      uint2 pk = pk_fp8x8(sh.sW[0][n] * 16.f, sh.sW[1][n] * 16.f,
                          sh.sW[2][n] * 16.f, sh.sW[3][n] * 16.f,
                          sh.sW[4][n] * 16.f, sh.sW[5][n] * 16.f,
                          sh.sW[6][n] * 16.f, sh.sW[7][n] * 16.f);
      const int ct = n >> 8, w = (n >> 6) & 3, cb = (n >> 4) & 3, l15 = n & 15;
      const int R = ct * 64 + ks4 * 16 + w * 4 + cb;
      const size_t off = (size_t)R * 2048 + part * 1024 + (qd * 16 + l15) * 16 + io;
      *(uint2*)&W2f8[off] = pk;
    }
  }
}

// ---------------- fused joint, MX-scaled fp8 (16x16x128, unity e8m0 scales),
// 48-row tile, (256,2) -- BYTE-IDENTICAL to R9/R11 (95.6us clean-container,
// VGPR 112, no scratch). R11's 118us on identical code+counters = external
// memory contention (busy% scaled with dur; FETCH/WRITE identical). FROZEN.
__global__ __launch_bounds__(256, 2)
void joint_kernel(const float* __restrict__ hEnc, const float* __restrict__ hDec,
                  const uchar_t* __restrict__ W2f8,
                  const float* __restrict__ b2, const int* __restrict__ tokens,
                  float* __restrict__ pD)
{
  __shared__ union SU {
    uchar_t X[ROWS * XPITCH];     // 48 x 520 = 24,960 B
    float red[4][ROWS][4];
  } sh;
  __shared__ float sb2[1024];     // b2 * LOG2E (padded with -1e30)

  const int tid = threadIdx.x;
  const int b  = blockIdx.z;
  const int t0 = blockIdx.y * 12;   // 17 blocks cover 200 (writes guarded)
  const int u0 = blockIdx.x * 4;    // 26 blocks cover 104 >= 101
  const int wave = tid >> 6;
  const int lane = tid & 63;
  const int l15 = lane & 15;
  const int quad = lane >> 4;

  // per-wave global B base: region R = g*16 + wave*4 + cb, lane-major 16B.
  // All offsets are compile-time constants folded per unrolled step.
  const uchar_t* gB = W2f8 + (size_t)wave * 8192 + (size_t)lane * 16;
  ifrag bv0[4], bv1[4];             // NAMED B double-buffers (64 VGPR)

#define LOADB(buf_, g_)                                                        \
  {                                                                            \
    *(int4*)&buf_[0]         = *(const int4*)(gB + (size_t)((g_)*16 + 0) * 2048);          \
    *(((int4*)&buf_[0]) + 1) = *(const int4*)(gB + (size_t)((g_)*16 + 0) * 2048 + 1024);   \
    *(int4*)&buf_[1]         = *(const int4*)(gB + (size_t)((g_)*16 + 1) * 2048);          \
    *(((int4*)&buf_[1]) + 1) = *(const int4*)(gB + (size_t)((g_)*16 + 1) * 2048 + 1024);   \
    *(int4*)&buf_[2]         = *(const int4*)(gB + (size_t)((g_)*16 + 2) * 2048);          \
    *(((int4*)&buf_[2]) + 1) = *(const int4*)(gB + (size_t)((g_)*16 + 2) * 2048 + 1024);   \
    *(int4*)&buf_[3]         = *(const int4*)(gB + (size_t)((g_)*16 + 3) * 2048);          \
    *(((int4*)&buf_[3]) + 1) = *(const int4*)(gB + (size_t)((g_)*16 + 3) * 2048 + 1024);   \
  }

  // tokens to regs (retire at the staging barrier)
  int tokv[4];
#pragma unroll
  for (int j = 0; j < 4; ++j)
    tokv[j] = (u0 + j < U_DIM) ? tokens[b * U_DIM + u0 + j] : -1;

  // b2 (scaled) -> LDS table (frees 16 VGPR vs the b2s register array)
  for (int i = tid; i < 1024; i += 256)
    sb2[i] = (i < V_DIM) ? b2[i] * LOG2E : -1e30f;

  // ---- X staging: per pass a wave owns one row; G = lane -> conflict-free
  // (hEnc already contains +b1)
  for (int i = tid; i < ROWS * 64; i += 256) {
    const int row = i >> 6;           // 0..47
    const int G = i & 63;
    const int tcl = min(t0 + (row >> 2), T_DIM - 1);
    const int ucl = min(u0 + (row & 3), U1 - 1);
    const float* er = hEnc + (size_t)(b * T_DIM + tcl) * K_INNER;
    const float* dr = hDec + (size_t)(b * U1 + ucl) * K_INNER;
    const int k = G << 3;
    float4 e0 = *(const float4*)(er + k);
    float4 e1 = *(const float4*)(er + k + 4);
    float4 d0 = *(const float4*)(dr + k);
    float4 d1 = *(const float4*)(dr + k + 4);
    uint2 pk = pk_fp8x8(tanh_fast(e0.x + d0.x), tanh_fast(e0.y + d0.y),
                        tanh_fast(e0.z + d0.z), tanh_fast(e0.w + d0.w),
                        tanh_fast(e1.x + d1.x), tanh_fast(e1.y + d1.y),
                        tanh_fast(e1.z + d1.z), tanh_fast(e1.w + d1.w));
    *(uint2*)&sh.X[row * XPITCH + (G << 3)] = pk;
  }

  // issue step-0 B loads: overlap the barrier (worst case drained there; then
  // the in-loop vmcnt(8) accounting is still correct -- it counts newest-8)
  LOADB(bv0, 0)
  __syncthreads();

  // A base: lane (l15,quad) holds row l15, k = ks4*128 + quad*32 + 0..31
  const uchar_t* aB = &sh.X[l15 * XPITCH + quad * 32];

  float sumexp[3][4], labelA[3][4], blankV[3][4];
#pragma unroll
  for (int i = 0; i < 3; ++i)
#pragma unroll
    for (int j = 0; j < 4; ++j) { sumexp[i][j] = 0.0f; labelA[i][j] = 0.0f; blankV[i][j] = 0.0f; }

  union AF { ifrag f; lfrag q[4]; };
  AF av0, av1, av2;                 // NAMED A fragments (24 VGPR)
  ffrag4 acc[3][4];

#define LDA(dst_, rb_, ks4_)                                                 \
  {                                                                          \
    const uchar_t* ap_ = aB + (rb_) * (16 * XPITCH) + (ks4_) * 128;          \
    dst_.q[0] = *(const lfrag*)(ap_);                                        \
    dst_.q[1] = *(const lfrag*)(ap_ + 8);                                    \
    dst_.q[2] = *(const lfrag*)(ap_ + 16);                                   \
    dst_.q[3] = *(const lfrag*)(ap_ + 24);                                   \
  }

#define MM1(rb_, cb_, AV, CUR)                                               \
  acc[rb_][cb_] = __builtin_amdgcn_mfma_scale_f32_16x16x128_f8f6f4(          \
      AV.f, CUR[cb_], acc[rb_][cb_], 0, 0, 0, 0x7f7f7f7f, 0, 0x7f7f7f7f);

  // one K-step: g = ct*4+ks4 (literal after the explicit 4-step sequence);
  // prefetch next step into NXT, consume CUR. vmcnt(8) = current 8 resident.
#define STEPK(g_, ks4_, CUR, NXT)                                            \
  {                                                                          \
    if ((g_) < 15) LOADB(NXT, (g_) + 1)                                      \
    LDA(av0, 0, ks4_)                                                        \
    LDA(av1, 1, ks4_)                                                        \
    LDA(av2, 2, ks4_)                                                        \
    if ((g_) < 15) { asm volatile("s_waitcnt vmcnt(8)" ::: "memory"); }      \
    else           { asm volatile("s_waitcnt vmcnt(0)" ::: "memory"); }      \
    __builtin_amdgcn_s_setprio(1);                                           \
    MM1(0, 0, av0, CUR) MM1(0, 1, av0, CUR) MM1(0, 2, av0, CUR) MM1(0, 3, av0, CUR) \
    MM1(1, 0, av1, CUR) MM1(1, 1, av1, CUR) MM1(1, 2, av1, CUR) MM1(1, 3, av1, CUR) \
    MM1(2, 0, av2, CUR) MM1(2, 1, av2, CUR) MM1(2, 2, av2, CUR) MM1(2, 3, av2, CUR) \
    __builtin_amdgcn_s_setprio(0);                                           \
  }

#pragma unroll
  for (int ct = 0; ct < 4; ++ct) {
    ffrag4 zero4 = {0.0f, 0.0f, 0.0f, 0.0f};
#pragma unroll
    for (int rb = 0; rb < 3; ++rb)
#pragma unroll
      for (int cb = 0; cb < 4; ++cb) acc[rb][cb] = zero4;

    STEPK(ct * 4 + 0, 0, bv0, bv1)
    STEPK(ct * 4 + 1, 1, bv1, bv0)
    STEPK(ct * 4 + 2, 2, bv0, bv1)
    STEPK(ct * 4 + 3, 3, bv1, bv0)

    // epilogue: acc = 16 x true logit (W2 scale); registers only + sb2
    // ds_reads (no vmem). Next ct's first B loads are already in flight ->
    // free latency cover.
#pragma unroll
    for (int cb = 0; cb < 4; ++cb) {
      const int v = ct * 256 + wave * 64 + cb * 16 + l15;
      const float bs = sb2[v];
#pragma unroll
      for (int rb = 0; rb < 3; ++rb)
#pragma unroll
        for (int reg = 0; reg < 4; ++reg) {
          float a = acc[rb][cb][reg];
          sumexp[rb][reg] += exp2f(fmaf(a, LOG2E16, bs));
          labelA[rb][reg] += (v == tokv[reg]) ? a : 0.0f;
        }
    }
    if (ct == 0 && wave == 0) {   // v==0 column lives on l15==0 lanes of cb 0
#pragma unroll
      for (int rb = 0; rb < 3; ++rb)
#pragma unroll
        for (int reg = 0; reg < 4; ++reg) blankV[rb][reg] = acc[rb][0][reg];
    }
  }
#undef STEPK
#undef MM1
#undef LDA
#undef LOADB

#pragma unroll
  for (int mask = 1; mask <= 8; mask <<= 1) {
#pragma unroll
    for (int rb = 0; rb < 3; ++rb)
#pragma unroll
      for (int reg = 0; reg < 4; ++reg) {
        sumexp[rb][reg] += __shfl_xor(sumexp[rb][reg], mask, 64);
        labelA[rb][reg] += __shfl_xor(labelA[rb][reg], mask, 64);
      }
  }

  __syncthreads();   // X reads done -> reuse union as red[]
  if (l15 == 0) {
#pragma unroll
    for (int rb = 0; rb < 3; ++rb)
#pragma unroll
      for (int reg = 0; reg < 4; ++reg) {
        int row = rb * 16 + quad * 4 + reg;
        sh.red[wave][row][0] = sumexp[rb][reg];
        sh.red[wave][row][1] = blankV[rb][reg];
        sh.red[wave][row][2] = labelA[rb][reg];
      }
  }
  __syncthreads();
  if (tid < ROWS) {
    float S  = sh.red[0][tid][0] + sh.red[1][tid][0] + sh.red[2][tid][0] + sh.red[3][tid][0];
    float Bl = sh.red[0][tid][1];
    float Lb = sh.red[0][tid][2] + sh.red[1][tid][2] + sh.red[2][tid][2] + sh.red[3][tid][2];
    int t = t0 + (tid >> 2);
    int u = u0 + (tid & 3);
    if (t < T_DIM && u < U1) {
      float lse2 = __log2f(S);                 // S = sum(exp(true logit))
      int tok = (u < U_DIM) ? tokens[b * U_DIM + u] : 0;
      int d = t + u;
      size_t idx = (((size_t)b * ND + d) * 128 + u) * 2;
      pD[idx]     = fmaf(Bl, LOG2E16, sb2[0])   - lse2;   // blank
      pD[idx + 1] = fmaf(Lb, LOG2E16, sb2[tok]) - lse2;   // label
    }
  }
}

// ---------------- RNNT DP, log2 domain, LDS-staged triple-buffered chunks --
// BYTE-IDENTICAL to R9/R11 (proven).
__global__ __launch_bounds__(256)
void dp_kernel(const float* __restrict__ pD,
               const int* __restrict__ outLen, const int* __restrict__ tokLen,
               float* __restrict__ outLoss)
{
  __shared__ __align__(16) float sD[4][3][CHUNK * 256];   // 96 KB triple buffer
  __shared__ float llsh[B_DIM];
  const int tid = threadIdx.x;
  const int wv = tid >> 6;                  // wave = batch
  const int lane = tid & 63;
  const float* src = pD + (size_t)wv * ND * 256;
  const int tIdx = outLen[wv] - 1;
  const int uIdx = tokLen[wv];
  const int dStar = tIdx + uIdx;
  const float NEG = -1e30f;
  const float blkStar = src[((size_t)dStar * 128 + uIdx) * 2];

  float aE = (lane == 0) ? 0.0f : NEG;      // log2 domain
  float aO = NEG;
  float ll2 = 0.0f;
  if (dStar == 0 && lane == 0) ll2 = blkStar;

  const int uE = 2 * lane;

#define ISSUE(c, buf)                                                         \
  {                                                                           \
    const float* g_ = src + (size_t)(c) * (CHUNK * 256);                      \
    float* l_ = &sD[wv][(buf)][0];                                            \
    _Pragma("unroll")                                                         \
    for (int j_ = 0; j_ < CHUNK; ++j_)                                        \
      __builtin_amdgcn_global_load_lds(                                       \
        (const __attribute__((address_space(1))) void*)(g_ + j_ * 256 + lane * 4), \
        (__attribute__((address_space(3))) void*)(l_ + j_ * 256), 16, 0, 0);  \
  }

  ISSUE(0, 0)
  ISSUE(1, 1)
#pragma unroll 1
  for (int c = 0; c < 38; ++c) {
    { const int nc = c + 2; const int cc = nc <= 37 ? nc : 37; ISSUE(cc, nc % 3) }
    asm volatile("s_waitcnt vmcnt(16)" ::: "memory");   // chunk c resident
    const float* buf = &sD[wv][c % 3][0];
    float4 qv[CHUNK];
#pragma unroll
    for (int j = 0; j < CHUNK; ++j)
      qv[j] = *(const float4*)&buf[j * 256 + uE * 2];
#pragma unroll
    for (int j = 0; j < CHUNK; ++j) {
      const int d = c * CHUNK + 1 + j;
      float4 q = qv[j];
      // q = (B[uE], L[uE], B[uE+1], L[uE+1]) at source diag d-1
      float aO_up = dpp_up1(aO, NEG);
      float labUp = dpp_up1(q.w, NEG);                // L[uE-1] @ d-1
      // uE cell
      float bt0 = aE + q.x, lt0 = aO_up + labUp;
      float mx0 = fmaxf(bt0, lt0), mn0 = fminf(bt0, lt0);
      float r0 = mx0 + __log2f(1.0f + exp2f(mn0 - mx0));
      int te = d - uE;
      float nE = ((uE <= U_DIM) && (te >= 0) && (te < T_DIM)) ? r0 : NEG;
      // uO cell
      float bt1 = aO + q.z, lt1 = aE + q.y;
      float mx1 = fmaxf(bt1, lt1), mn1 = fminf(bt1, lt1);
      float r1 = mx1 + __log2f(1.0f + exp2f(mn1 - mx1));
      int to = te - 1;
      float nO = ((uE + 1 <= U_DIM) && (to >= 0) && (to < T_DIM)) ? r1 : NEG;
      aE = nE; aO = nO;
      if (d == dStar) {
        if (uIdx == uE)          ll2 = nE + blkStar;
        else if (uIdx == uE + 1) ll2 = nO + blkStar;
      }
    }
  }
#undef ISSUE

#pragma unroll
  for (int mask = 1; mask < 64; mask <<= 1) ll2 += __shfl_xor(ll2, mask, 64);
  if (lane == 0) llsh[wv] = ll2;
  __syncthreads();
  if (tid == 0)
    outLoss[0] = -(llsh[0] + llsh[1] + llsh[2] + llsh[3]) * 0.25f * LN2;
}

// ---------------- launch
extern "C" void kernel_launch(void* const* d_in, const int* in_sizes, int n_in,
                              void* d_out, int out_size, void* d_ws, size_t ws_size,
                              hipStream_t stream)
{
  const float* enc    = (const float*)d_in[0];
  const float* dec    = (const float*)d_in[1];
  const int*   tokens = (const int*)d_in[2];
  const int*   outLen = (const int*)d_in[3];
  const int*   tokLen = (const int*)d_in[4];
  const float* W1     = (const float*)d_in[5];
  const float* b1     = (const float*)d_in[6];
  const float* W2     = (const float*)d_in[7];
  const float* b2     = (const float*)d_in[8];
  float* out = (float*)d_out;

  char* ws = (char*)d_ws;
  float*   hEnc = (float*)(ws + 0);           // 800*512*4     = 1,638,400
  float*   hDec = (float*)(ws + 1638400);     // 404*512*4     =   827,392
  uchar_t* W2f8 = (uchar_t*)(ws + 2465792);   // 256 regions*2048 = 524,288 (16-aligned)
  float*   pD   = (float*)(ws + 2990080);     // 4*300*128*2*4 = 1,228,800
                                              // + 16KB tail pad for dp chunk-37 overread

  prep_kernel<<<dim3(666), dim3(512), 0, stream>>>(enc, dec, W1, W2, b1, hEnc, hDec, W2f8);
  joint_kernel<<<dim3(26, 17, B_DIM), dim3(256), 0, stream>>>(hEnc, hDec, W2f8, b2, tokens, pD);
  dp_kernel<<<dim3(1), dim3(256), 0, stream>>>(pD, outLen, tokLen, out);
}